// Round 10
// baseline (70.005 us; speedup 1.0000x reference)
//
#include <hip/hip_runtime.h>
#include <utility>

#define NC 32     // num_capsule
#define DC 16     // dim_capsule
#define INC 144   // input capsules
#define IND 8     // input dim
#define NT 512
#define LG_S 152  // halves per b row (76 dw), 16B-aligned rows

typedef _Float16 h2 __attribute__((ext_vector_type(2)));
typedef _Float16 h4 __attribute__((ext_vector_type(4)));
typedef _Float16 h8 __attribute__((ext_vector_type(8)));
typedef float f4 __attribute__((ext_vector_type(4)));

union H8 { h8 v; h2 p[4]; };
union HU { h2 h; unsigned u; };

// Compile-time loop: every register-array index is a constant GEP (rule #20).
template <class F, int... Is>
__device__ __forceinline__ void sfor_impl(F&& f, std::integer_sequence<int, Is...>) {
    (f(std::integral_constant<int, Is>{}), ...);
}
template <int N, class F>
__device__ __forceinline__ void sfor(F&& f) {
    sfor_impl((F&&)f, std::make_integer_sequence<int, N>{});
}

#if __has_builtin(__builtin_amdgcn_fdot2)
__device__ __forceinline__ float fdot2(h2 a, h2 b, float c) {
    return __builtin_amdgcn_fdot2(a, b, c, false);
}
#else
__device__ __forceinline__ float fdot2(h2 a, h2 b, float c) {
    return c + (float)a[0] * (float)b[0] + (float)a[1] * (float)b[1];
}
#endif

__global__ void convw_kernel(const float* __restrict__ W, _Float16* __restrict__ Wh) {
    int i = blockIdx.x * 256 + threadIdx.x;  // 147456 f4 groups
    f4 v = reinterpret_cast<const f4*>(W)[i];
    h4 h;
    h[0] = (_Float16)v[0]; h[1] = (_Float16)v[1];
    h[2] = (_Float16)v[2]; h[3] = (_Float16)v[3];
    reinterpret_cast<h4*>(Wh)[i] = h;
}

__device__ __forceinline__ float squash16(float s) {
    float n2 = s * s;
    n2 += __shfl_xor(n2, 1, 16);
    n2 += __shfl_xor(n2, 2, 16);
    n2 += __shfl_xor(n2, 4, 16);
    n2 += __shfl_xor(n2, 8, 16);
    return s * (n2 / ((1.0f + n2) * sqrtf(n2 + 1e-7f)));
}

template <typename WT>
__global__ __launch_bounds__(NT)
void caps_kernel(const float* __restrict__ xg, const WT* __restrict__ Wg,
                 float* __restrict__ out) {
    __shared__ _Float16 x_h[INC * IND];   // 2304 B
    __shared__ _Float16 lg[NC * LG_S];    // 9728 B  (b-major logits/coefficients)

    const int t = threadIdx.x;
    const int b = t >> 4;   // capsule
    const int d = t & 15;   // dim
    const int a = blockIdx.x;

    // ---- load x[a]: 1152 floats = 288 f4, convert to fp16 ----
    if (t < (INC * IND) / 4) {
        f4 v = reinterpret_cast<const f4*>(xg + (size_t)a * (INC * IND))[t];
        h4 hv;
        hv[0] = (_Float16)v[0]; hv[1] = (_Float16)v[1];
        hv[2] = (_Float16)v[2]; hv[3] = (_Float16)v[3];
        *reinterpret_cast<h4*>(x_h + t * 4) = hv;
    }
    __syncthreads();

    // ---- Phase H: hat[b][c][d] -> hreg (h2-packed over c); s0 falls out free ----
    h2 hreg[72];
    float s0 = 0.0f;
    {
        const WT* wp = Wg + ((size_t)(b * INC) * DC + d) * IND;
        sfor<INC>([&](auto C) {
            constexpr int c = C.value;
            H8 xv;
            xv.v = *reinterpret_cast<const h8*>(x_h + c * IND);  // broadcast
            float acc;
            if constexpr (sizeof(WT) == 2) {
                H8 wv;
                wv.v = *reinterpret_cast<const h8*>(wp + (size_t)c * (DC * IND));
                acc = fdot2(wv.p[0], xv.p[0], 0.f);
                acc = fdot2(wv.p[1], xv.p[1], acc);
                acc = fdot2(wv.p[2], xv.p[2], acc);
                acc = fdot2(wv.p[3], xv.p[3], acc);
            } else {
                const float* wf = reinterpret_cast<const float*>(wp) + (size_t)c * (DC * IND);
                f4 w0 = *reinterpret_cast<const f4*>(wf);
                f4 w1 = *reinterpret_cast<const f4*>(wf + 4);
                acc = (float)xv.v[0] * w0[0];
                acc = fmaf((float)xv.v[1], w0[1], acc);
                acc = fmaf((float)xv.v[2], w0[2], acc);
                acc = fmaf((float)xv.v[3], w0[3], acc);
                acc = fmaf((float)xv.v[4], w1[0], acc);
                acc = fmaf((float)xv.v[5], w1[1], acc);
                acc = fmaf((float)xv.v[6], w1[2], acc);
                acc = fmaf((float)xv.v[7], w1[3], acc);
            }
            s0 += acc;
            hreg[c >> 1][c & 1] = (_Float16)acc;
        });
    }
    float o = squash16(s0 * (1.0f / 32.0f));  // softmax(0) uniform -> s0 free

    float lgr[9];
    sfor<9>([&](auto J) { lgr[J.value] = 0.f; });  // fp32 logit master

    for (int it = 0; it < 2; ++it) {
        // ---- B-pass (in registers): logit[b][16j+d] = sum_d' o_d' * hat[16j+d][d']
        // 16-lane recursive-halving tree over the b-group; no LDS hat needed.
        {
            h2 oh2;
            oh2[0] = (_Float16)o; oh2[1] = (_Float16)o;
            sfor<9>([&](auto J) {
                constexpr int j = J.value;
                h2 qp[8];
                sfor<8>([&](auto I) {          // q pairs: c = 16j+2i, 16j+2i+1
                    constexpr int i = I.value;
                    qp[i] = oh2 * hreg[8 * j + i];   // v_pk_mul_f16
                });
                const bool h8s = (d & 8) != 0;
                sfor<4>([&](auto I) {          // fold lanes differing in bit3
                    constexpr int i = I.value;
                    h2 send = h8s ? qp[i] : qp[i + 4];
                    h2 keep = h8s ? qp[i + 4] : qp[i];
                    HU su; su.h = send;
                    HU ru; ru.u = __shfl_xor(su.u, 8, 16);
                    qp[i] = keep + ru.h;       // v_pk_add_f16
                });
                const bool h4s = (d & 4) != 0;
                sfor<2>([&](auto I) {
                    constexpr int i = I.value;
                    h2 send = h4s ? qp[i] : qp[i + 2];
                    h2 keep = h4s ? qp[i + 2] : qp[i];
                    HU su; su.h = send;
                    HU ru; ru.u = __shfl_xor(su.u, 4, 16);
                    qp[i] = keep + ru.h;
                });
                {
                    const bool h2s = (d & 2) != 0;
                    h2 send = h2s ? qp[0] : qp[1];
                    h2 keep = h2s ? qp[1] : qp[0];
                    HU su; su.h = send;
                    HU ru; ru.u = __shfl_xor(su.u, 2, 16);
                    qp[0] = keep + ru.h;
                }
                {
                    HU su; su.h = qp[0];
                    HU ru; ru.u = __shfl_xor(su.u, 1, 16);
                    h2 tot = qp[0] + ru.h;     // both c's of pair p = d>>1, full 16-lane sum
                    HU tu; tu.h = tot;
                    unsigned short sel = (d & 1) ? (unsigned short)(tu.u >> 16)
                                                 : (unsigned short)(tu.u & 0xffffu);
                    union { unsigned short s; _Float16 hv; } cv;
                    cv.s = sel;
                    lgr[j] += (float)cv.hv;    // logit for c = 16j + d
                }
                lg[b * LG_S + 16 * j + d] = (_Float16)lgr[j];
            });
        }
        __syncthreads();

        // ---- softmax over 32 capsules: 2 threads per c, 16 bb's each ----
        if (t < 2 * INC) {
            const int c = t >> 1;
            const int hh = t & 1;
            float v[16];
            sfor<16>([&](auto I) {
                constexpr int i = I.value;
                v[i] = (float)lg[(hh * 16 + i) * LG_S + c];
            });
            float m = v[0];
            sfor<15>([&](auto I) { m = fmaxf(m, v[I.value + 1]); });
            m = fmaxf(m, __shfl_xor(m, 1));
            float S = 0.f;
            sfor<16>([&](auto I) {
                constexpr int i = I.value;
                v[i] = __expf(v[i] - m);
                S += v[i];
            });
            S += __shfl_xor(S, 1);
            float inv = 1.0f / S;
            sfor<16>([&](auto I) {
                constexpr int i = I.value;
                lg[(hh * 16 + i) * LG_S + c] = (_Float16)(v[i] * inv);
            });
        }
        __syncthreads();

        // ---- S-pass from registers: s = sum_c cc[b][c] * hat[c][d] ----
        {
            const _Float16* cp = lg + b * LG_S;   // broadcast reads within b-group
            float sA = 0.f, sB = 0.f;
            sfor<18>([&](auto M) {
                constexpr int m2 = M.value;
                H8 cc;
                cc.v = *reinterpret_cast<const h8*>(cp + m2 * 8);
                sA = fdot2(cc.p[0], hreg[m2 * 4 + 0], sA);
                sB = fdot2(cc.p[1], hreg[m2 * 4 + 1], sB);
                sA = fdot2(cc.p[2], hreg[m2 * 4 + 2], sA);
                sB = fdot2(cc.p[3], hreg[m2 * 4 + 3], sB);
            });
            float oo = squash16(sA + sB);
            if (it == 0) {
                o = oo;
                __syncthreads();   // S-reads of lg done before next B-pass writes
            } else {
                out[(size_t)a * (NC * DC) + t] = oo;
            }
        }
    }
}

extern "C" void kernel_launch(void* const* d_in, const int* in_sizes, int n_in,
                              void* d_out, int out_size, void* d_ws, size_t ws_size,
                              hipStream_t stream) {
    const float* x = (const float*)d_in[0];
    const float* W = (const float*)d_in[1];
    float* out = (float*)d_out;

    const size_t WH_BYTES = (size_t)NC * INC * DC * IND * 2;  // 1179648

    if (ws_size >= WH_BYTES) {
        _Float16* Wh = (_Float16*)d_ws;
        hipLaunchKernelGGL(convw_kernel, dim3((NC * INC * DC * IND / 4) / 256),
                           dim3(256), 0, stream, W, Wh);
        hipLaunchKernelGGL(caps_kernel<_Float16>, dim3(512), dim3(NT), 0,
                           stream, x, Wh, out);
    } else {
        hipLaunchKernelGGL(caps_kernel<float>, dim3(512), dim3(NT), 0,
                           stream, x, W, out);
    }
}

// Round 11
// 70.000 us; speedup vs baseline: 1.0001x; 1.0001x over previous
//
#include <hip/hip_runtime.h>
#include <utility>

#define NC 32     // num_capsule
#define DC 16     // dim_capsule
#define INC 144   // input capsules
#define IND 8     // input dim
#define NT 512
#define LG_S 152  // halves per b row (76 dw), 16B-aligned rows

typedef _Float16 h2 __attribute__((ext_vector_type(2)));
typedef _Float16 h4 __attribute__((ext_vector_type(4)));
typedef _Float16 h8 __attribute__((ext_vector_type(8)));
typedef float f4 __attribute__((ext_vector_type(4)));

union H8 { h8 v; h2 p[4]; };
union HU { h2 h; unsigned u; };

// Compile-time loop: every register-array index is a constant GEP (rule #20).
template <class F, int... Is>
__device__ __forceinline__ void sfor_impl(F&& f, std::integer_sequence<int, Is...>) {
    (f(std::integral_constant<int, Is>{}), ...);
}
template <int N, class F>
__device__ __forceinline__ void sfor(F&& f) {
    sfor_impl((F&&)f, std::make_integer_sequence<int, N>{});
}

#if __has_builtin(__builtin_amdgcn_fdot2)
__device__ __forceinline__ float fdot2(h2 a, h2 b, float c) {
    return __builtin_amdgcn_fdot2(a, b, c, false);
}
#else
__device__ __forceinline__ float fdot2(h2 a, h2 b, float c) {
    return c + (float)a[0] * (float)b[0] + (float)a[1] * (float)b[1];
}
#endif

__global__ void convw_kernel(const float* __restrict__ W, _Float16* __restrict__ Wh) {
    int i = blockIdx.x * 256 + threadIdx.x;  // 147456 f4 groups
    f4 v = reinterpret_cast<const f4*>(W)[i];
    h4 h;
    h[0] = (_Float16)v[0]; h[1] = (_Float16)v[1];
    h[2] = (_Float16)v[2]; h[3] = (_Float16)v[3];
    reinterpret_cast<h4*>(Wh)[i] = h;
}

__device__ __forceinline__ float squash16(float s) {
    float n2 = s * s;
    n2 += __shfl_xor(n2, 1, 16);
    n2 += __shfl_xor(n2, 2, 16);
    n2 += __shfl_xor(n2, 4, 16);
    n2 += __shfl_xor(n2, 8, 16);
    return s * (n2 / ((1.0f + n2) * sqrtf(n2 + 1e-7f)));
}

template <typename WT>
__global__ __launch_bounds__(NT, 2)  // 2 waves/EU min -> 128-VGPR budget (proven r4/r5); hreg[72]+temps ~105 fits
void caps_kernel(const float* __restrict__ xg, const WT* __restrict__ Wg,
                 float* __restrict__ out) {
    __shared__ _Float16 x_h[INC * IND];   // 2304 B
    __shared__ _Float16 lg[NC * LG_S];    // 9728 B  (b-major logits/coefficients)

    const int t = threadIdx.x;
    const int b = t >> 4;   // capsule
    const int d = t & 15;   // dim
    const int a = blockIdx.x;

    // ---- load x[a]: 1152 floats = 288 f4, convert to fp16 ----
    if (t < (INC * IND) / 4) {
        f4 v = reinterpret_cast<const f4*>(xg + (size_t)a * (INC * IND))[t];
        h4 hv;
        hv[0] = (_Float16)v[0]; hv[1] = (_Float16)v[1];
        hv[2] = (_Float16)v[2]; hv[3] = (_Float16)v[3];
        *reinterpret_cast<h4*>(x_h + t * 4) = hv;
    }
    __syncthreads();

    // ---- Phase H: hat[b][c][d] -> hreg (h2-packed over c); s0 falls out free ----
    h2 hreg[72];
    float s0 = 0.0f;
    {
        const WT* wp = Wg + ((size_t)(b * INC) * DC + d) * IND;
        sfor<INC>([&](auto C) {
            constexpr int c = C.value;
            H8 xv;
            xv.v = *reinterpret_cast<const h8*>(x_h + c * IND);  // broadcast
            float acc;
            if constexpr (sizeof(WT) == 2) {
                H8 wv;
                wv.v = *reinterpret_cast<const h8*>(wp + (size_t)c * (DC * IND));
                acc = fdot2(wv.p[0], xv.p[0], 0.f);
                acc = fdot2(wv.p[1], xv.p[1], acc);
                acc = fdot2(wv.p[2], xv.p[2], acc);
                acc = fdot2(wv.p[3], xv.p[3], acc);
            } else {
                const float* wf = reinterpret_cast<const float*>(wp) + (size_t)c * (DC * IND);
                f4 w0 = *reinterpret_cast<const f4*>(wf);
                f4 w1 = *reinterpret_cast<const f4*>(wf + 4);
                acc = (float)xv.v[0] * w0[0];
                acc = fmaf((float)xv.v[1], w0[1], acc);
                acc = fmaf((float)xv.v[2], w0[2], acc);
                acc = fmaf((float)xv.v[3], w0[3], acc);
                acc = fmaf((float)xv.v[4], w1[0], acc);
                acc = fmaf((float)xv.v[5], w1[1], acc);
                acc = fmaf((float)xv.v[6], w1[2], acc);
                acc = fmaf((float)xv.v[7], w1[3], acc);
            }
            s0 += acc;
            hreg[c >> 1][c & 1] = (_Float16)acc;
        });
    }
    float o = squash16(s0 * (1.0f / 32.0f));  // softmax(0) uniform -> s0 free

    float lgr[9];
    sfor<9>([&](auto J) { lgr[J.value] = 0.f; });  // fp32 logit master

    for (int it = 0; it < 2; ++it) {
        // ---- B-pass (in registers): logit[b][16j+d] = sum_d' o_d' * hat[16j+d][d']
        // 16-lane recursive-halving tree over the b-group; no LDS hat needed.
        {
            h2 oh2;
            oh2[0] = (_Float16)o; oh2[1] = (_Float16)o;
            sfor<9>([&](auto J) {
                constexpr int j = J.value;
                h2 qp[8];
                sfor<8>([&](auto I) {          // q pairs: c = 16j+2i, 16j+2i+1
                    constexpr int i = I.value;
                    qp[i] = oh2 * hreg[8 * j + i];   // v_pk_mul_f16
                });
                const bool h8s = (d & 8) != 0;
                sfor<4>([&](auto I) {          // fold lanes differing in bit3
                    constexpr int i = I.value;
                    h2 send = h8s ? qp[i] : qp[i + 4];
                    h2 keep = h8s ? qp[i + 4] : qp[i];
                    HU su; su.h = send;
                    HU ru; ru.u = __shfl_xor(su.u, 8, 16);
                    qp[i] = keep + ru.h;       // v_pk_add_f16
                });
                const bool h4s = (d & 4) != 0;
                sfor<2>([&](auto I) {
                    constexpr int i = I.value;
                    h2 send = h4s ? qp[i] : qp[i + 2];
                    h2 keep = h4s ? qp[i + 2] : qp[i];
                    HU su; su.h = send;
                    HU ru; ru.u = __shfl_xor(su.u, 4, 16);
                    qp[i] = keep + ru.h;
                });
                {
                    const bool h2s = (d & 2) != 0;
                    h2 send = h2s ? qp[0] : qp[1];
                    h2 keep = h2s ? qp[1] : qp[0];
                    HU su; su.h = send;
                    HU ru; ru.u = __shfl_xor(su.u, 2, 16);
                    qp[0] = keep + ru.h;
                }
                {
                    HU su; su.h = qp[0];
                    HU ru; ru.u = __shfl_xor(su.u, 1, 16);
                    h2 tot = qp[0] + ru.h;     // both c's of pair p = d>>1, full 16-lane sum
                    HU tu; tu.h = tot;
                    unsigned short sel = (d & 1) ? (unsigned short)(tu.u >> 16)
                                                 : (unsigned short)(tu.u & 0xffffu);
                    union { unsigned short s; _Float16 hv; } cv;
                    cv.s = sel;
                    lgr[j] += (float)cv.hv;    // logit for c = 16j + d
                }
                lg[b * LG_S + 16 * j + d] = (_Float16)lgr[j];
            });
        }
        __syncthreads();

        // ---- softmax over 32 capsules: 2 threads per c, 16 bb's each ----
        if (t < 2 * INC) {
            const int c = t >> 1;
            const int hh = t & 1;
            float v[16];
            sfor<16>([&](auto I) {
                constexpr int i = I.value;
                v[i] = (float)lg[(hh * 16 + i) * LG_S + c];
            });
            float m = v[0];
            sfor<15>([&](auto I) { m = fmaxf(m, v[I.value + 1]); });
            m = fmaxf(m, __shfl_xor(m, 1));
            float S = 0.f;
            sfor<16>([&](auto I) {
                constexpr int i = I.value;
                v[i] = __expf(v[i] - m);
                S += v[i];
            });
            S += __shfl_xor(S, 1);
            float inv = 1.0f / S;
            sfor<16>([&](auto I) {
                constexpr int i = I.value;
                lg[(hh * 16 + i) * LG_S + c] = (_Float16)(v[i] * inv);
            });
        }
        __syncthreads();

        // ---- S-pass from registers: s = sum_c cc[b][c] * hat[c][d] ----
        {
            const _Float16* cp = lg + b * LG_S;   // broadcast reads within b-group
            float sA = 0.f, sB = 0.f;
            sfor<18>([&](auto M) {
                constexpr int m2 = M.value;
                H8 cc;
                cc.v = *reinterpret_cast<const h8*>(cp + m2 * 8);
                sA = fdot2(cc.p[0], hreg[m2 * 4 + 0], sA);
                sB = fdot2(cc.p[1], hreg[m2 * 4 + 1], sB);
                sA = fdot2(cc.p[2], hreg[m2 * 4 + 2], sA);
                sB = fdot2(cc.p[3], hreg[m2 * 4 + 3], sB);
            });
            float oo = squash16(sA + sB);
            if (it == 0) {
                o = oo;
                __syncthreads();   // S-reads of lg done before next B-pass writes
            } else {
                out[(size_t)a * (NC * DC) + t] = oo;
            }
        }
    }
}

extern "C" void kernel_launch(void* const* d_in, const int* in_sizes, int n_in,
                              void* d_out, int out_size, void* d_ws, size_t ws_size,
                              hipStream_t stream) {
    const float* x = (const float*)d_in[0];
    const float* W = (const float*)d_in[1];
    float* out = (float*)d_out;

    const size_t WH_BYTES = (size_t)NC * INC * DC * IND * 2;  // 1179648

    if (ws_size >= WH_BYTES) {
        _Float16* Wh = (_Float16*)d_ws;
        hipLaunchKernelGGL(convw_kernel, dim3((NC * INC * DC * IND / 4) / 256),
                           dim3(256), 0, stream, W, Wh);
        hipLaunchKernelGGL(caps_kernel<_Float16>, dim3(512), dim3(NT), 0,
                           stream, x, Wh, out);
    } else {
        hipLaunchKernelGGL(caps_kernel<float>, dim3(512), dim3(NT), 0,
                           stream, x, W, out);
    }
}

// Round 14
// 56.399 us; speedup vs baseline: 1.2413x; 1.2412x over previous
//
#include <hip/hip_runtime.h>

#define NC 32     // num_capsule
#define DC 16     // dim_capsule
#define INC 144   // input capsules
#define IND 8     // input dim
#define NT 512    // threads: (b 0..31) x (cg 0..15)
#define LG_S 152  // halves per b row of logits

typedef _Float16 h2 __attribute__((ext_vector_type(2)));
typedef _Float16 h4v __attribute__((ext_vector_type(4)));
typedef _Float16 h8 __attribute__((ext_vector_type(8)));
typedef float f4 __attribute__((ext_vector_type(4)));

union H8 { h8 v; h2 p[4]; _Float16 e[8]; };

#if __has_builtin(__builtin_amdgcn_fdot2)
__device__ __forceinline__ float fdot2(h2 a, h2 b, float c) {
    return __builtin_amdgcn_fdot2(a, b, c, false);
}
#else
__device__ __forceinline__ float fdot2(h2 a, h2 b, float c) {
    return c + (float)a[0] * (float)b[0] + (float)a[1] * (float)b[1];
}
#endif

// Convert+TRANSPOSE W: fp32 [b][c][d][i] -> fp16 h8-slots [(b*9+k)*16+d][cg],
// c = cg + 16k. Lane cg's H-phase load then reads slot base+cg: 16B/lane,
// contiguous across the 16 same-b lanes -> perfectly coalesced L2 stream.
// 73728 h8 slots total -> grid 288 x 256 (r12 bug: 576 overran W 2x -> fault).
__global__ void convw_kernel(const float* __restrict__ W, _Float16* __restrict__ Wh) {
    int i = blockIdx.x * 256 + threadIdx.x;          // h8 slot 0..73727
    int cg = i & 15, d = (i >> 4) & 15, bk = i >> 8; // bk = b*9+k, 0..287
    int k = bk % 9, b = bk / 9;
    const float* s = W + (((size_t)b * INC + cg + 16 * k) * DC + d) * IND;
    f4 v0 = *reinterpret_cast<const f4*>(s);
    f4 v1 = *reinterpret_cast<const f4*>(s + 4);
    H8 o;
    o.e[0] = (_Float16)v0[0]; o.e[1] = (_Float16)v0[1];
    o.e[2] = (_Float16)v0[2]; o.e[3] = (_Float16)v0[3];
    o.e[4] = (_Float16)v1[0]; o.e[5] = (_Float16)v1[1];
    o.e[6] = (_Float16)v1[2]; o.e[7] = (_Float16)v1[3];
    *reinterpret_cast<h8*>(Wh + (size_t)i * 8) = o.v;
}

#define R9(M)  M(0) M(1) M(2) M(3) M(4) M(5) M(6) M(7) M(8)
#define R16(M) M(0) M(1) M(2) M(3) M(4) M(5) M(6) M(7) M(8) M(9) M(10) M(11) M(12) M(13) M(14) M(15)

template <typename WT>
__global__ __launch_bounds__(NT)
__attribute__((amdgpu_waves_per_eu(2, 4)))  // budget 256: no forced spill at ~130 live
void caps_kernel(const float* __restrict__ xg, const WT* __restrict__ Wg,
                 float* __restrict__ out) {
    __shared__ __align__(16) _Float16 x_h[INC * IND];  // 2304 B
    __shared__ __align__(16) _Float16 lg[NC * LG_S];   // 9728 B

    const int t = threadIdx.x;
    const int b = t >> 4;    // capsule
    const int cg = t & 15;   // c-group: this thread owns c = cg + 16k, all 16 d
    const int a = blockIdx.x;

    // ---- load x[a]: 1152 floats = 288 f4 -> fp16 LDS ----
    if (t < 288) {
        f4 v = reinterpret_cast<const f4*>(xg + (size_t)a * (INC * IND))[t];
        h4v hv;
        hv[0] = (_Float16)v[0]; hv[1] = (_Float16)v[1];
        hv[2] = (_Float16)v[2]; hv[3] = (_Float16)v[3];
        *reinterpret_cast<h4v*>(x_h + t * 4) = hv;
    }
    __syncthreads();

    // hat[b][c][d] for this thread's 9 c's: 18 NAMED h8 (no array, no alloca)
#define DECLH(K) h8 hc##K##L, hc##K##H;
    R9(DECLH)
#define DECLS(D) float s##D;
    R16(DECLS)
#define ZEROS(D) s##D = 0.f;

    // one d of one c: W row dot x row (4 fdot2), stash fp16, accumulate s0_d
#define HD1(T, E, DG) { \
    float ac; \
    if constexpr (sizeof(WT) == 2) { \
        H8 w; w.v = *reinterpret_cast<const h8*>(wr + (DG) * 128 + cg * 8); \
        ac = fdot2(w.p[0], xv.p[0], 0.f); \
        ac = fdot2(w.p[1], xv.p[1], ac); \
        ac = fdot2(w.p[2], xv.p[2], ac); \
        ac = fdot2(w.p[3], xv.p[3], ac); \
    } else { \
        const float* wf = reinterpret_cast<const float*>(wr) + (DG) * IND; \
        f4 w0 = *reinterpret_cast<const f4*>(wf); \
        f4 w1 = *reinterpret_cast<const f4*>(wf + 4); \
        ac = (float)xv.e[0] * w0[0]; \
        ac = fmaf((float)xv.e[1], w0[1], ac); \
        ac = fmaf((float)xv.e[2], w0[2], ac); \
        ac = fmaf((float)xv.e[3], w0[3], ac); \
        ac = fmaf((float)xv.e[4], w1[0], ac); \
        ac = fmaf((float)xv.e[5], w1[1], ac); \
        ac = fmaf((float)xv.e[6], w1[2], ac); \
        ac = fmaf((float)xv.e[7], w1[3], ac); \
    } \
    T.e[E] = (_Float16)ac; s##DG += ac; }

#define HSTEP(K) { \
    const int c = cg + 16 * (K); \
    H8 xv; xv.v = *reinterpret_cast<const h8*>(x_h + c * IND); \
    const WT* wr; \
    if constexpr (sizeof(WT) == 2) wr = Wg + ((size_t)(b * 9 + (K)) * 2048); \
    else wr = Wg + ((size_t)(b * INC + c) * (DC * IND)); \
    H8 tL, tH; \
    HD1(tL,0,0) HD1(tL,1,1) HD1(tL,2,2) HD1(tL,3,3) \
    HD1(tL,4,4) HD1(tL,5,5) HD1(tL,6,6) HD1(tL,7,7) \
    HD1(tH,0,8) HD1(tH,1,9) HD1(tH,2,10) HD1(tH,3,11) \
    HD1(tH,4,12) HD1(tH,5,13) HD1(tH,6,14) HD1(tH,7,15) \
    hc##K##L = tL.v; hc##K##H = tH.v; }

    R16(ZEROS)
    R9(HSTEP)

    // 16-lane fp32 butterfly allreduce over the b-group (lanes share b)
#define BF1(D) s##D += __shfl_xor(s##D, 1, 16);
#define BF2(D) s##D += __shfl_xor(s##D, 2, 16);
#define BF4(D) s##D += __shfl_xor(s##D, 4, 16);
#define BF8(D) s##D += __shfl_xor(s##D, 8, 16);
#define SCL(D) s##D *= (1.0f / 32.0f);
    R16(BF1) R16(BF2) R16(BF4) R16(BF8)
    R16(SCL)  // softmax(0) uniform coefficients

#define SUMSQ (s0*s0+s1*s1+s2*s2+s3*s3+s4*s4+s5*s5+s6*s6+s7*s7+ \
               s8*s8+s9*s9+s10*s10+s11*s11+s12*s12+s13*s13+s14*s14+s15*s15)

    h8 oLv, oHv;
#define PACKO { \
    float n2 = SUMSQ; \
    float ff = n2 / ((1.0f + n2) * sqrtf(n2 + 1e-7f)); \
    H8 pl, ph; \
    pl.e[0]=(_Float16)(s0*ff);  pl.e[1]=(_Float16)(s1*ff); \
    pl.e[2]=(_Float16)(s2*ff);  pl.e[3]=(_Float16)(s3*ff); \
    pl.e[4]=(_Float16)(s4*ff);  pl.e[5]=(_Float16)(s5*ff); \
    pl.e[6]=(_Float16)(s6*ff);  pl.e[7]=(_Float16)(s7*ff); \
    ph.e[0]=(_Float16)(s8*ff);  ph.e[1]=(_Float16)(s9*ff); \
    ph.e[2]=(_Float16)(s10*ff); ph.e[3]=(_Float16)(s11*ff); \
    ph.e[4]=(_Float16)(s12*ff); ph.e[5]=(_Float16)(s13*ff); \
    ph.e[6]=(_Float16)(s14*ff); ph.e[7]=(_Float16)(s15*ff); \
    oLv = pl.v; oHv = ph.v; }
    PACKO

#define DECLG(K) float lgr##K = 0.f;
    R9(DECLG)

    // B-pass: logit[b][c] += o . hat[b][c][:] -- fully thread-local
#define BSTEP(K) { \
    H8 hl, hh; hl.v = hc##K##L; hh.v = hc##K##H; \
    H8 ol, oh; ol.v = oLv; oh.v = oHv; \
    float dt = fdot2(hl.p[0], ol.p[0], 0.f); \
    dt = fdot2(hl.p[1], ol.p[1], dt); \
    dt = fdot2(hl.p[2], ol.p[2], dt); \
    dt = fdot2(hl.p[3], ol.p[3], dt); \
    dt = fdot2(hh.p[0], oh.p[0], dt); \
    dt = fdot2(hh.p[1], oh.p[1], dt); \
    dt = fdot2(hh.p[2], oh.p[2], dt); \
    dt = fdot2(hh.p[3], oh.p[3], dt); \
    lgr##K += dt; \
    lg[b * LG_S + cg + 16 * (K)] = (_Float16)lgr##K; }

    // S-pass: fp32 fma over own 9 c's, butterfly later
#define SSTEP(K) { \
    float cf = (float)lg[b * LG_S + cg + 16 * (K)]; \
    H8 hl, hh; hl.v = hc##K##L; hh.v = hc##K##H; \
    s0  = fmaf(cf, (float)hl.e[0], s0);  s1  = fmaf(cf, (float)hl.e[1], s1); \
    s2  = fmaf(cf, (float)hl.e[2], s2);  s3  = fmaf(cf, (float)hl.e[3], s3); \
    s4  = fmaf(cf, (float)hl.e[4], s4);  s5  = fmaf(cf, (float)hl.e[5], s5); \
    s6  = fmaf(cf, (float)hl.e[6], s6);  s7  = fmaf(cf, (float)hl.e[7], s7); \
    s8  = fmaf(cf, (float)hh.e[0], s8);  s9  = fmaf(cf, (float)hh.e[1], s9); \
    s10 = fmaf(cf, (float)hh.e[2], s10); s11 = fmaf(cf, (float)hh.e[3], s11); \
    s12 = fmaf(cf, (float)hh.e[4], s12); s13 = fmaf(cf, (float)hh.e[5], s13); \
    s14 = fmaf(cf, (float)hh.e[6], s14); s15 = fmaf(cf, (float)hh.e[7], s15); }

    for (int it = 0; it < 2; ++it) {
        R9(BSTEP)
        __syncthreads();

        // softmax over 32 capsules: 2 threads per c, 16 bb's each, named regs
        if (t < 2 * INC) {
            const int c = t >> 1;
            const int rb = (t & 1) * 16;
#define SMR(I) float v##I = (float)lg[(rb + I) * LG_S + c];
            R16(SMR)
            float m = fmaxf(v0, v1);
#define SMM(I) m = fmaxf(m, v##I);
            SMM(2) SMM(3) SMM(4) SMM(5) SMM(6) SMM(7) SMM(8) SMM(9)
            SMM(10) SMM(11) SMM(12) SMM(13) SMM(14) SMM(15)
            m = fmaxf(m, __shfl_xor(m, 1));
            float S = 0.f;
#define SME(I) v##I = __expf(v##I - m); S += v##I;
            R16(SME)
            S += __shfl_xor(S, 1);
            float inv = 1.0f / S;
#define SMW(I) lg[(rb + I) * LG_S + c] = (_Float16)(v##I * inv);
            R16(SMW)
        }
        __syncthreads();

        R16(ZEROS)
        R9(SSTEP)
        R16(BF1) R16(BF2) R16(BF4) R16(BF8)

        if (it == 0) {
            PACKO
            __syncthreads();  // S-reads of lg done before next B-pass writes
        } else {
            float n2 = SUMSQ;
            float ff = n2 / ((1.0f + n2) * sqrtf(n2 + 1e-7f));
            float r = s0;
            if (cg == 1) r = s1;   if (cg == 2) r = s2;   if (cg == 3) r = s3;
            if (cg == 4) r = s4;   if (cg == 5) r = s5;   if (cg == 6) r = s6;
            if (cg == 7) r = s7;   if (cg == 8) r = s8;   if (cg == 9) r = s9;
            if (cg == 10) r = s10; if (cg == 11) r = s11; if (cg == 12) r = s12;
            if (cg == 13) r = s13; if (cg == 14) r = s14; if (cg == 15) r = s15;
            out[(size_t)a * (NC * DC) + t] = r * ff;  // out[a][b][d=cg], coalesced
        }
    }
}

extern "C" void kernel_launch(void* const* d_in, const int* in_sizes, int n_in,
                              void* d_out, int out_size, void* d_ws, size_t ws_size,
                              hipStream_t stream) {
    const float* x = (const float*)d_in[0];
    const float* W = (const float*)d_in[1];
    float* out = (float*)d_out;

    const size_t WH_BYTES = (size_t)NC * INC * DC * IND * 2;  // 1179648

    if (ws_size >= WH_BYTES) {
        _Float16* Wh = (_Float16*)d_ws;
        hipLaunchKernelGGL(convw_kernel, dim3(288), dim3(256), 0, stream, W, Wh);
        hipLaunchKernelGGL(caps_kernel<_Float16>, dim3(512), dim3(NT), 0,
                           stream, x, Wh, out);
    } else {
        hipLaunchKernelGGL(caps_kernel<float>, dim3(512), dim3(NT), 0,
                           stream, x, W, out);
    }
}